// Round 4
// baseline (282.510 us; speedup 1.0000x reference)
//
#include <hip/hip_runtime.h>

// Problem constants
#define LSEQ 512      // L
#define DDIM 256      // D
#define PDIM 128      // PAIR_DIM
#define BLROWS 1024   // B * L
#define ROWS 4        // h-rows per block in projection kernel (256 blocks -> all CUs)

// Native clang vector type for __builtin_nontemporal_store (HIP's float4 is a
// class type the builtin rejects).
typedef float nfloat4 __attribute__((ext_vector_type(4)));

// Kernel 1: P1[bl][p]  = dot(h[bl,:], W[p, 0:256])
//           P2b[bl][p] = dot(h[bl,:], W[p, 256:512]) + bias[p]
// 256 blocks x 256 threads; threads 0..127 -> P1, 128..255 -> P2b.
__global__ __launch_bounds__(256) void pair_proj(
    const float* __restrict__ h, const float* __restrict__ W,
    const float* __restrict__ bias, float* __restrict__ P1,
    float* __restrict__ P2b)
{
    __shared__ float4 hsh[ROWS * (DDIM / 4)];  // 4 rows x 64 float4 = 4 KB

    const int t   = threadIdx.x;
    const int bl0 = blockIdx.x * ROWS;

    // Cooperative load of 4 h-rows (256 float4) into LDS, coalesced.
    const float4* h4 = (const float4*)h + (size_t)bl0 * (DDIM / 4);
    hsh[t] = h4[t];
    __syncthreads();

    const int p    = t & (PDIM - 1);
    const int half = t >> 7;  // 0 -> W1 (P1), 1 -> W2 (P2b)

    const float4* w4 = (const float4*)(W + (size_t)p * (2 * DDIM) + half * DDIM);

    float acc[ROWS];
#pragma unroll
    for (int r = 0; r < ROWS; ++r) acc[r] = 0.f;

#pragma unroll 8
    for (int d4 = 0; d4 < DDIM / 4; ++d4) {
        const float4 w = w4[d4];
#pragma unroll
        for (int r = 0; r < ROWS; ++r) {
            const float4 hh = hsh[r * (DDIM / 4) + d4];  // wave-uniform -> LDS broadcast
            acc[r] = fmaf(w.x, hh.x, acc[r]);
            acc[r] = fmaf(w.y, hh.y, acc[r]);
            acc[r] = fmaf(w.z, hh.z, acc[r]);
            acc[r] = fmaf(w.w, hh.w, acc[r]);
        }
    }

    float* dst      = half ? P2b : P1;
    const float bb  = half ? bias[p] : 0.f;
#pragma unroll
    for (int r = 0; r < ROWS; ++r)
        dst[(size_t)(bl0 + r) * PDIM + p] = acc[r] + bb;
}

// Kernel 2: out[b,i,j,p] = P1[b,i,p] + P2b[b,j,p]
// Each block owns an 8i x 64j x 128p output tile (256 KB).
// All operand data (8 P1 rows + 64 P2b rows, sliced per-thread) is loaded
// into registers ONCE (16 independent loads), then 64 pure streaming
// nontemporal float4 stores per thread — zero dependent loads in steady state.
// Thread layout: p4 = t&31 (float4 along p), jq = t>>5 (8 j's per group).
// Each (i,g) store instruction: wave writes 1 KB contiguous; block writes
// 4 KB contiguous per (i,g).
__global__ __launch_bounds__(256) void bcast_add(
    const float4* __restrict__ P1, const float4* __restrict__ P2b,
    float4* __restrict__ out)
{
    const int t  = threadIdx.x;
    const int p4 = t & 31;
    const int jq = t >> 5;            // 0..7
    const int bt = blockIdx.x;        // 0..1023
    const int jt = bt & 7;            // j-tile index (64 j per tile)
    const int it = (bt >> 3) & 63;    // i-tile index (8 i per tile)
    const int b  = bt >> 9;           // batch
    const int i0 = it * 8;
    const int j0 = jt * 64;

    float4 a[8], v[8];

    // 8 P1 rows, this thread's p4 slice (address uniform across jq -> broadcast-friendly)
    const float4* p1 = P1 + ((size_t)(b * LSEQ + i0)) * 32 + p4;
#pragma unroll
    for (int i = 0; i < 8; ++i) a[i] = p1[(size_t)i * 32];

    // 64 P2b rows: thread jq covers j = j0 + g*8 + jq; per-instruction wave
    // footprint is 1 KB contiguous.
    const float4* p2 = P2b + ((size_t)(b * LSEQ + j0 + jq)) * 32 + p4;
#pragma unroll
    for (int g = 0; g < 8; ++g) v[g] = p2[(size_t)g * 8 * 32];

    // out float4 index: ((b*512 + i)*512 + j)*32 + p4, i = i0+i, j = j0 + g*8 + jq
    float4* dst = out + (((size_t)(b * LSEQ + i0)) * LSEQ + (j0 + jq)) * 32 + p4;

#pragma unroll
    for (int i = 0; i < 8; ++i) {
#pragma unroll
        for (int g = 0; g < 8; ++g) {
            const float4 ai = a[i];
            const float4 vg = v[g];
            nfloat4 r;
            r.x = ai.x + vg.x;
            r.y = ai.y + vg.y;
            r.z = ai.z + vg.z;
            r.w = ai.w + vg.w;
            __builtin_nontemporal_store(
                r, reinterpret_cast<nfloat4*>(
                       dst + (size_t)i * (LSEQ * 32) + (size_t)g * 256));
        }
    }
}

extern "C" void kernel_launch(void* const* d_in, const int* in_sizes, int n_in,
                              void* d_out, int out_size, void* d_ws, size_t ws_size,
                              hipStream_t stream) {
    const float* h    = (const float*)d_in[0];  // (2, 512, 256) fp32
    const float* W    = (const float*)d_in[1];  // (128, 512)    fp32
    const float* bias = (const float*)d_in[2];  // (128,)        fp32

    float* P1  = (float*)d_ws;                  // 1024 x 128 fp32 = 512 KB
    float* P2b = P1 + (size_t)BLROWS * PDIM;    // 1024 x 128 fp32 = 512 KB

    pair_proj<<<dim3(BLROWS / ROWS), dim3(256), 0, stream>>>(h, W, bias, P1, P2b);

    bcast_add<<<dim3(1024), dim3(256), 0, stream>>>(
        (const float4*)P1, (const float4*)P2b, (float4*)d_out);
}

// Round 5
// 275.907 us; speedup vs baseline: 1.0239x; 1.0239x over previous
//
#include <hip/hip_runtime.h>

// Problem constants
#define LSEQ 512      // L
#define DDIM 256      // D
#define PDIM 128      // PAIR_DIM
#define BLROWS 1024   // B * L
#define ROWS 4        // h-rows per block in projection kernel (256 blocks -> all CUs)

// Kernel 1: P1[bl][p]  = dot(h[bl,:], W[p, 0:256])
//           P2b[bl][p] = dot(h[bl,:], W[p, 256:512]) + bias[p]
// 256 blocks x 256 threads; threads 0..127 -> P1, 128..255 -> P2b.
__global__ __launch_bounds__(256) void pair_proj(
    const float* __restrict__ h, const float* __restrict__ W,
    const float* __restrict__ bias, float* __restrict__ P1,
    float* __restrict__ P2b)
{
    __shared__ float4 hsh[ROWS * (DDIM / 4)];  // 4 rows x 64 float4 = 4 KB

    const int t   = threadIdx.x;
    const int bl0 = blockIdx.x * ROWS;

    // Cooperative load of 4 h-rows (256 float4) into LDS, coalesced.
    const float4* h4 = (const float4*)h + (size_t)bl0 * (DDIM / 4);
    hsh[t] = h4[t];
    __syncthreads();

    const int p    = t & (PDIM - 1);
    const int half = t >> 7;  // 0 -> W1 (P1), 1 -> W2 (P2b)

    const float4* w4 = (const float4*)(W + (size_t)p * (2 * DDIM) + half * DDIM);

    float acc[ROWS];
#pragma unroll
    for (int r = 0; r < ROWS; ++r) acc[r] = 0.f;

#pragma unroll 8
    for (int d4 = 0; d4 < DDIM / 4; ++d4) {
        const float4 w = w4[d4];
#pragma unroll
        for (int r = 0; r < ROWS; ++r) {
            const float4 hh = hsh[r * (DDIM / 4) + d4];  // wave-uniform -> LDS broadcast
            acc[r] = fmaf(w.x, hh.x, acc[r]);
            acc[r] = fmaf(w.y, hh.y, acc[r]);
            acc[r] = fmaf(w.z, hh.z, acc[r]);
            acc[r] = fmaf(w.w, hh.w, acc[r]);
        }
    }

    float* dst      = half ? P2b : P1;
    const float bb  = half ? bias[p] : 0.f;
#pragma unroll
    for (int r = 0; r < ROWS; ++r)
        dst[(size_t)(bl0 + r) * PDIM + p] = acc[r] + bb;
}

// Kernel 2: out[b,i,j,p] = P1[b,i,p] + P2b[b,j,p]
// Fill-like max-TLP form: 8192 blocks x 256 threads (32 waves/CU), each block
// owns one (b,i) and a 64-j octant -> 32 KB contiguous output.
// Per thread: 1 P1 load (invariant) + 8 P2b loads (L2-resident), precompute
// the 8 sums, then 8 pure plain dwordx4 stores. Shallow dependency, ~46 VGPR,
// plain stores (nt proven a no-op last round).
// Wave footprint per store instruction: 1 KB contiguous (lanes 0-31 = row j,
// lanes 32-63 = row j+1). The 4 waves of a block tile 4 KB per g-step.
__global__ __launch_bounds__(256) void bcast_add(
    const float4* __restrict__ P1, const float4* __restrict__ P2b,
    float4* __restrict__ out)
{
    const int t  = threadIdx.x;
    const int p4 = t & 31;
    const int jq = t >> 5;            // 0..7
    const int bt = blockIdx.x;        // 0..8191
    const int jo = bt & 7;            // j-octant (64 j per octant)
    const int bi = bt >> 3;           // b*512 + i, 0..1023
    const int b  = bi >> 9;           // batch
    const int j0 = jo * 64;

    // Invariant P1 slice for this (b,i).
    const float4 a = P1[(size_t)bi * 32 + p4];

    // 8 P2b rows: j = j0 + g*8 + jq.
    const float4* p2 = P2b + ((size_t)(b * LSEQ + j0 + jq)) * 32 + p4;
    float4*      dst = out + ((size_t)bi * LSEQ + (j0 + jq)) * 32 + p4;

    float4 r[8];
#pragma unroll
    for (int g = 0; g < 8; ++g) {
        const float4 v = p2[(size_t)g * 8 * 32];
        r[g].x = a.x + v.x;
        r[g].y = a.y + v.y;
        r[g].z = a.z + v.z;
        r[g].w = a.w + v.w;
    }

#pragma unroll
    for (int g = 0; g < 8; ++g)
        dst[(size_t)g * 256] = r[g];
}

extern "C" void kernel_launch(void* const* d_in, const int* in_sizes, int n_in,
                              void* d_out, int out_size, void* d_ws, size_t ws_size,
                              hipStream_t stream) {
    const float* h    = (const float*)d_in[0];  // (2, 512, 256) fp32
    const float* W    = (const float*)d_in[1];  // (128, 512)    fp32
    const float* bias = (const float*)d_in[2];  // (128,)        fp32

    float* P1  = (float*)d_ws;                  // 1024 x 128 fp32 = 512 KB
    float* P2b = P1 + (size_t)BLROWS * PDIM;    // 1024 x 128 fp32 = 512 KB

    pair_proj<<<dim3(BLROWS / ROWS), dim3(256), 0, stream>>>(h, W, bias, P1, P2b);

    bcast_add<<<dim3(BLROWS * 8), dim3(256), 0, stream>>>(
        (const float4*)P1, (const float4*)P2b, (float4*)d_out);
}